// Round 2
// baseline (481.071 us; speedup 1.0000x reference)
//
#include <hip/hip_runtime.h>
#include <hip/hip_bf16.h>
#include <type_traits>

typedef __bf16 bf16x8 __attribute__((ext_vector_type(8)));
typedef __bf16 bf16x4 __attribute__((ext_vector_type(4)));
typedef float f32x4 __attribute__((ext_vector_type(4)));

#define B_ 2
#define L_ 2048
#define D_ 1024
#define H_ 16
#define DK_ 64

__device__ __forceinline__ __bf16 f2bf(float f) { return (__bf16)f; }

// C[M,N] = A[M,K] @ B[K,N] + bias[N]; fp32 accumulate, bf16 MFMA.
// TA: float (convert at staging) or __bf16 (direct). B is always float.
// TC: float or __bf16.
// Block 256 threads = 4 waves; tile 64(M) x 64(N), BK=32.
template <typename TA, typename TC>
__global__ __launch_bounds__(256) void gemm_bias(const TA* __restrict__ A,
                                                 const float* __restrict__ Bm,
                                                 const float* __restrict__ bias,
                                                 TC* __restrict__ C,
                                                 int M, int N, int K) {
  __shared__ __bf16 As[64][40];   // [m][k], +8 pad, row stride 80B (16B-aligned)
  __shared__ __bf16 Bt[64][40];   // transposed: [n][k]

  const int tid  = threadIdx.x;
  const int wave = tid >> 6;
  const int lane = tid & 63;
  const int quad = lane >> 4;
  const int l16  = lane & 15;
  const int m0 = blockIdx.y * 64;
  const int n0 = blockIdx.x * 64;

  f32x4 acc[4];
  acc[0] = acc[1] = acc[2] = acc[3] = (f32x4){0.f, 0.f, 0.f, 0.f};

  for (int k0 = 0; k0 < K; k0 += 32) {
    __syncthreads();
    // ---- A tile 64 x 32 ----
    if constexpr (std::is_same<TA, float>::value) {
      // 512 float4 chunks, 2 per thread
#pragma unroll
      for (int i = tid; i < 512; i += 256) {
        const int row = i >> 3, kc = (i & 7) * 4;
        const float4 a4 = *(const float4*)&A[(size_t)(m0 + row) * K + k0 + kc];
        bf16x4 t;
        t[0] = f2bf(a4.x); t[1] = f2bf(a4.y); t[2] = f2bf(a4.z); t[3] = f2bf(a4.w);
        *(bf16x4*)&As[row][kc] = t;
      }
    } else {
      const int row = tid >> 2, kc = (tid & 3) * 8;
      *(bf16x8*)&As[row][kc] = *(const bf16x8*)&A[(size_t)(m0 + row) * K + k0 + kc];
    }
    // ---- B tile 32 x 64 (float), transposed into Bt[n][k] ----
#pragma unroll
    for (int i = tid; i < 512; i += 256) {
      const int kr = i >> 4, nc = (i & 15) * 4;
      const float4 b4 = *(const float4*)&Bm[(size_t)(k0 + kr) * N + n0 + nc];
      Bt[nc + 0][kr] = f2bf(b4.x);
      Bt[nc + 1][kr] = f2bf(b4.y);
      Bt[nc + 2][kr] = f2bf(b4.z);
      Bt[nc + 3][kr] = f2bf(b4.w);
    }
    __syncthreads();

    // A frag: A[m = lane&15][k = quad*8+j]  (m offset by wave*16)
    bf16x8 a = *(const bf16x8*)&As[wave * 16 + l16][quad * 8];
#pragma unroll
    for (int nt = 0; nt < 4; ++nt) {
      // B frag: B[k = quad*8+j][n = lane&15]  == Bt[n][k]
      bf16x8 b = *(const bf16x8*)&Bt[nt * 16 + l16][quad * 8];
      acc[nt] = __builtin_amdgcn_mfma_f32_16x16x32_bf16(a, b, acc[nt], 0, 0, 0);
    }
  }

  // C/D layout: col = lane&15, row = quad*4 + reg
#pragma unroll
  for (int nt = 0; nt < 4; ++nt) {
    const int col = n0 + nt * 16 + l16;
    const float bvf = bias[col];
#pragma unroll
    for (int r = 0; r < 4; ++r) {
      const int row = m0 + wave * 16 + quad * 4 + r;
      C[(size_t)row * N + col] = (TC)(acc[nt][r] + bvf);
    }
  }
}

// Flash attention over packed QKV (B*L, 3*D) bf16 workspace.
// Head h columns: q at h*192+[0,64), k at +64, v at +128.
// Block = 256 thr = 4 waves, handles (b, h, 64 queries); wave owns 16 queries.
__global__ __launch_bounds__(256) void attn(const __bf16* __restrict__ QKV,
                                            __bf16* __restrict__ Out) {
  __shared__ __bf16 Ks[32][72];      // [key][d 0..63]
  __shared__ __bf16 Vt[64][40];      // transposed: [d][key 0..31]
  __shared__ __bf16 Ps[4][16][40];   // per-wave P: [m][key 0..31]

  const int tid  = threadIdx.x;
  const int wave = tid >> 6;
  const int lane = tid & 63;
  const int quad = lane >> 4;
  const int l16  = lane & 15;

  const int qt = blockIdx.x;
  const int h  = blockIdx.y;
  const int b  = blockIdx.z;
  const size_t rowbase = (size_t)b * L_;
  const int q0 = qt * 64;
  const int qcol = h * 3 * DK_;

  // Q fragments pinned for the whole key loop: A[m=lane&15][k=quad*8+j]
  bf16x8 qf[2];
  {
    const size_t qrow = rowbase + q0 + wave * 16 + l16;
#pragma unroll
    for (int s = 0; s < 2; ++s)
      qf[s] = *(const bf16x8*)&QKV[qrow * (3 * D_) + qcol + s * 32 + quad * 8];
  }

  float mrow[4], lrow[4], alpha[4];
  f32x4 o[4];
#pragma unroll
  for (int r = 0; r < 4; ++r) { mrow[r] = -3.0e38f; lrow[r] = 0.f; }
  o[0] = o[1] = o[2] = o[3] = (f32x4){0.f, 0.f, 0.f, 0.f};

  const int sk = tid >> 3;           // key within tile (0..31)
  const int sd = (tid & 7) * 8;      // d chunk

  for (int kt = 0; kt < L_ / 32; ++kt) {
    const int kb = kt * 32;
    __syncthreads();
    {
      const size_t krow = (rowbase + kb + sk) * (size_t)(3 * D_);
      *(bf16x8*)&Ks[sk][sd] = *(const bf16x8*)&QKV[krow + qcol + DK_ + sd];
      bf16x8 vv = *(const bf16x8*)&QKV[krow + qcol + 2 * DK_ + sd];
#pragma unroll
      for (int j = 0; j < 8; ++j) Vt[sd + j][sk] = vv[j];
    }
    __syncthreads();

    // S = Q K^T : B frag B[k=d][n=key] == Ks[key][d]
    f32x4 s0 = {0.f, 0.f, 0.f, 0.f}, s1 = {0.f, 0.f, 0.f, 0.f};
    {
      bf16x8 b0  = *(const bf16x8*)&Ks[l16][quad * 8];
      bf16x8 b0b = *(const bf16x8*)&Ks[l16][32 + quad * 8];
      s0 = __builtin_amdgcn_mfma_f32_16x16x32_bf16(qf[0], b0,  s0, 0, 0, 0);
      s0 = __builtin_amdgcn_mfma_f32_16x16x32_bf16(qf[1], b0b, s0, 0, 0, 0);
      bf16x8 b1  = *(const bf16x8*)&Ks[16 + l16][quad * 8];
      bf16x8 b1b = *(const bf16x8*)&Ks[16 + l16][32 + quad * 8];
      s1 = __builtin_amdgcn_mfma_f32_16x16x32_bf16(qf[0], b1,  s1, 0, 0, 0);
      s1 = __builtin_amdgcn_mfma_f32_16x16x32_bf16(qf[1], b1b, s1, 0, 0, 0);
    }

    // Online softmax. Lane holds rows m=quad*4+r, keys l16 and l16+16.
#pragma unroll
    for (int r = 0; r < 4; ++r) {
      float a0 = s0[r] * 0.125f;
      float a1 = s1[r] * 0.125f;
      float mx = fmaxf(a0, a1);
#pragma unroll
      for (int off = 1; off < 16; off <<= 1) mx = fmaxf(mx, __shfl_xor(mx, off));
      const float mnew = fmaxf(mrow[r], mx);
      const float al = __expf(mrow[r] - mnew);
      const float p0 = __expf(a0 - mnew);
      const float p1 = __expf(a1 - mnew);
      float sm = p0 + p1;
#pragma unroll
      for (int off = 1; off < 16; off <<= 1) sm += __shfl_xor(sm, off);
      lrow[r] = lrow[r] * al + sm;
      mrow[r] = mnew;
      alpha[r] = al;
      Ps[wave][quad * 4 + r][l16]      = f2bf(p0);
      Ps[wave][quad * 4 + r][16 + l16] = f2bf(p1);
    }
#pragma unroll
    for (int dt = 0; dt < 4; ++dt)
#pragma unroll
      for (int r = 0; r < 4; ++r) o[dt][r] *= alpha[r];

    __syncthreads();   // P visible (LDS round-trip C-layout -> A-layout)

    // O += P V : A frag = Ps[m=lane&15][k=quad*8+j]; B frag == Vt[d][key]
    bf16x8 pa = *(const bf16x8*)&Ps[wave][l16][quad * 8];
#pragma unroll
    for (int dt = 0; dt < 4; ++dt) {
      bf16x8 vb = *(const bf16x8*)&Vt[dt * 16 + l16][quad * 8];
      o[dt] = __builtin_amdgcn_mfma_f32_16x16x32_bf16(pa, vb, o[dt], 0, 0, 0);
    }
  }

#pragma unroll
  for (int dt = 0; dt < 4; ++dt)
#pragma unroll
    for (int r = 0; r < 4; ++r) {
      const size_t row = rowbase + q0 + wave * 16 + quad * 4 + r;
      Out[row * D_ + h * DK_ + dt * 16 + l16] = f2bf(o[dt][r] / lrow[r]);
    }
}

extern "C" void kernel_launch(void* const* d_in, const int* in_sizes, int n_in,
                              void* d_out, int out_size, void* d_ws, size_t ws_size,
                              hipStream_t stream) {
  (void)in_sizes; (void)n_in; (void)out_size; (void)ws_size;
  const float* x     = (const float*)d_in[0];
  const float* w_qkv = (const float*)d_in[1];
  const float* b_qkv = (const float*)d_in[2];
  const float* w_out = (const float*)d_in[3];
  const float* b_out = (const float*)d_in[4];
  float* out = (float*)d_out;

  __bf16* qkv = (__bf16*)d_ws;                          // [4096, 3072] bf16 (25.2 MB)
  __bf16* att = qkv + (size_t)(B_ * L_) * (3 * D_);     // [4096, 1024] bf16 (8.4 MB)

  dim3 blk(256);
  gemm_bias<float, __bf16><<<dim3((3 * D_) / 64, (B_ * L_) / 64), blk, 0, stream>>>(
      x, w_qkv, b_qkv, qkv, B_ * L_, 3 * D_, D_);
  attn<<<dim3(L_ / 64, H_, B_), blk, 0, stream>>>(qkv, att);
  gemm_bias<__bf16, float><<<dim3(D_ / 64, (B_ * L_) / 64), blk, 0, stream>>>(
      att, w_out, b_out, out, B_ * L_, D_, D_);
}

// Round 3
// 297.322 us; speedup vs baseline: 1.6180x; 1.6180x over previous
//
#include <hip/hip_runtime.h>
#include <hip/hip_bf16.h>

typedef __bf16 bf16x8 __attribute__((ext_vector_type(8)));
typedef __bf16 bf16x4 __attribute__((ext_vector_type(4)));
typedef float f32x4 __attribute__((ext_vector_type(4)));

#define B_ 2
#define L_ 2048
#define D_ 1024
#define H_ 16
#define DK_ 64

__device__ __forceinline__ __bf16 f2bf(float f) { return (__bf16)f; }

// ---------- elementwise fp32 -> bf16 ----------
__global__ __launch_bounds__(256) void cvt_bf16(const float* __restrict__ X,
                                                __bf16* __restrict__ Y) {
  const int i = (blockIdx.x * 256 + threadIdx.x) * 8;
  const float4 a = *(const float4*)&X[i];
  const float4 b = *(const float4*)&X[i + 4];
  bf16x8 o;
  o[0] = f2bf(a.x); o[1] = f2bf(a.y); o[2] = f2bf(a.z); o[3] = f2bf(a.w);
  o[4] = f2bf(b.x); o[5] = f2bf(b.y); o[6] = f2bf(b.z); o[7] = f2bf(b.w);
  *(bf16x8*)&Y[i] = o;
}

// ---------- transpose + convert: W[K,N] fp32 -> WT[N,K] bf16 ----------
__global__ __launch_bounds__(256) void transpose_cvt(const float* __restrict__ W,
                                                     __bf16* __restrict__ WT,
                                                     int K, int N) {
  __shared__ float ts[32][33];
  const int nt = blockIdx.x * 32, kt = blockIdx.y * 32;
  const int r = threadIdx.x >> 3, c4 = (threadIdx.x & 7) * 4;
  const float4 v = *(const float4*)&W[(size_t)(kt + r) * N + nt + c4];
  ts[r][c4 + 0] = v.x; ts[r][c4 + 1] = v.y; ts[r][c4 + 2] = v.z; ts[r][c4 + 3] = v.w;
  __syncthreads();
  bf16x4 o;
  o[0] = f2bf(ts[c4 + 0][r]); o[1] = f2bf(ts[c4 + 1][r]);
  o[2] = f2bf(ts[c4 + 2][r]); o[3] = f2bf(ts[c4 + 3][r]);
  *(bf16x4*)&WT[(size_t)(nt + r) * K + kt + c4] = o;
}

// ---------- m97-style GEMM: C[M,N] = A[M,K] @ BT[N,K]^T + bias ----------
// 128x128 tile, BK=32, 256 thr = 4 waves (2x2), global_load_lds width 16.
template <typename TC>
__global__ __launch_bounds__(256) void gemm_bt(const __bf16* __restrict__ A,
                                               const __bf16* __restrict__ BT,
                                               const float* __restrict__ bias,
                                               TC* __restrict__ C,
                                               int M, int N, int K) {
  __shared__ __bf16 As[128 * 32];   // [m][k] contiguous (no pad: global_load_lds)
  __shared__ __bf16 Bs[128 * 32];   // [n][k] contiguous

  const int tid  = threadIdx.x;
  const int wave = tid >> 6, lane = tid & 63, quad = lane >> 4, l16 = lane & 15;
  const int wr = wave >> 1, wc = wave & 1;
  const int m0 = blockIdx.y * 128, n0 = blockIdx.x * 128;

  f32x4 acc[4][4];
#pragma unroll
  for (int i = 0; i < 4; ++i)
#pragma unroll
    for (int j = 0; j < 4; ++j) acc[i][j] = (f32x4){0.f, 0.f, 0.f, 0.f};

  for (int k0 = 0; k0 < K; k0 += 32) {
    __syncthreads();
#pragma unroll
    for (int p = 0; p < 2; ++p) {
      const int c = p * 256 + tid;          // 512 chunks of 16B per tile
      const int row = c >> 2, kc = c & 3;   // 4 chunks per 64B row
      __builtin_amdgcn_global_load_lds(
          (const __attribute__((address_space(1))) void*)&A[(size_t)(m0 + row) * K + k0 + kc * 8],
          (__attribute__((address_space(3))) void*)&As[c * 8], 16, 0, 0);
      __builtin_amdgcn_global_load_lds(
          (const __attribute__((address_space(1))) void*)&BT[(size_t)(n0 + row) * K + k0 + kc * 8],
          (__attribute__((address_space(3))) void*)&Bs[c * 8], 16, 0, 0);
    }
    __syncthreads();

    bf16x8 af[4], bfr[4];
#pragma unroll
    for (int mt = 0; mt < 4; ++mt)
      af[mt] = *(const bf16x8*)&As[(wr * 64 + mt * 16 + l16) * 32 + quad * 8];
#pragma unroll
    for (int nt = 0; nt < 4; ++nt)
      bfr[nt] = *(const bf16x8*)&Bs[(wc * 64 + nt * 16 + l16) * 32 + quad * 8];
#pragma unroll
    for (int mt = 0; mt < 4; ++mt)
#pragma unroll
      for (int nt = 0; nt < 4; ++nt)
        acc[mt][nt] = __builtin_amdgcn_mfma_f32_16x16x32_bf16(af[mt], bfr[nt], acc[mt][nt], 0, 0, 0);
  }

  // C/D: col = l16, row = quad*4 + r
#pragma unroll
  for (int nt = 0; nt < 4; ++nt) {
    const int col = n0 + wc * 64 + nt * 16 + l16;
    const float bv = bias[col];
#pragma unroll
    for (int mt = 0; mt < 4; ++mt)
#pragma unroll
      for (int r = 0; r < 4; ++r) {
        const int row = m0 + wr * 64 + mt * 16 + quad * 4 + r;
        C[(size_t)row * N + col] = (TC)(acc[mt][nt][r] + bv);
      }
  }
}

// ---------- flash attention v2: S^T = K Q^T ----------
// Block 128 = 2 waves; wave owns 16 queries; key tile 64. Grid (64, H, B).
// K frags: direct global->register. V: block-shared LDS transpose (2 barriers).
// P^T->A-frag via per-wave LDS (no barrier).
__global__ __launch_bounds__(128, 4) void attn(const __bf16* __restrict__ QKV,
                                               __bf16* __restrict__ Out) {
  __shared__ __bf16 Vt[64][72];      // [d][key], stride 144B (16B-aligned rows)
  __shared__ __bf16 Ps[2][16][72];   // per-wave: [query][key]

  const int tid  = threadIdx.x;
  const int wave = tid >> 6, lane = tid & 63, quad = lane >> 4, l16 = lane & 15;
  const int qt = blockIdx.x, h = blockIdx.y, b = blockIdx.z;
  const size_t rowbase = (size_t)b * L_;
  const int q0 = qt * 32 + wave * 16;
  const int qcol = h * 3 * DK_;
  const int SD = 3 * D_;

  // Q B-frags (pinned): B[k=d][n=query=l16] = Q[l16][dc*32 + quad*8 + j]
  bf16x8 qf[2];
#pragma unroll
  for (int dc = 0; dc < 2; ++dc)
    qf[dc] = *(const bf16x8*)&QKV[(rowbase + q0 + l16) * SD + qcol + dc * 32 + quad * 8];

  float m = -3.0e38f, l = 0.f;
  f32x4 o[4];
  o[0] = o[1] = o[2] = o[3] = (f32x4){0.f, 0.f, 0.f, 0.f};

  const int vkey = tid >> 1;          // 0..63
  const int vdc0 = (tid & 1) * 4;     // chunk half

  for (int kt = 0; kt < L_ / 64; ++kt) {
    const int kb = kt * 64;

    // ---- stage V^T (block-shared) ----
    __syncthreads();
    bf16x8 vv[4];
#pragma unroll
    for (int p = 0; p < 4; ++p)
      vv[p] = *(const bf16x8*)&QKV[(rowbase + kb + vkey) * SD + qcol + 2 * DK_ + (vdc0 + p) * 8];
#pragma unroll
    for (int p = 0; p < 4; ++p)
#pragma unroll
      for (int j = 0; j < 8; ++j)
        Vt[(vdc0 + p) * 8 + j][vkey] = vv[p][j];
    __syncthreads();

    // ---- S^T = K Q^T : A = K (direct global), B = qf ----
    f32x4 st[4];
    st[0] = st[1] = st[2] = st[3] = (f32x4){0.f, 0.f, 0.f, 0.f};
#pragma unroll
    for (int kc = 0; kc < 4; ++kc) {
      const __bf16* kp = &QKV[(rowbase + kb + kc * 16 + l16) * SD + qcol + DK_ + quad * 8];
      bf16x8 a0 = *(const bf16x8*)kp;
      bf16x8 a1 = *(const bf16x8*)(kp + 32);
      st[kc] = __builtin_amdgcn_mfma_f32_16x16x32_bf16(a0, qf[0], st[kc], 0, 0, 0);
      st[kc] = __builtin_amdgcn_mfma_f32_16x16x32_bf16(a1, qf[1], st[kc], 0, 0, 0);
    }

    // ---- online softmax (lane: 16 keys of query l16) ----
    float s[16];
#pragma unroll
    for (int kc = 0; kc < 4; ++kc)
#pragma unroll
      for (int r = 0; r < 4; ++r) s[kc * 4 + r] = st[kc][r] * 0.125f;
    float mx = s[0];
#pragma unroll
    for (int i = 1; i < 16; ++i) mx = fmaxf(mx, s[i]);
    mx = fmaxf(mx, __shfl_xor(mx, 16));
    mx = fmaxf(mx, __shfl_xor(mx, 32));
    const float mnew = fmaxf(m, mx);
    const float alpha = __expf(m - mnew);
    float sum = 0.f;
#pragma unroll
    for (int i = 0; i < 16; ++i) { s[i] = __expf(s[i] - mnew); sum += s[i]; }
    sum += __shfl_xor(sum, 16);
    sum += __shfl_xor(sum, 32);
    l = l * alpha + sum;
    m = mnew;

    // P^T -> Ps[query][key]: lane holds keys kc*16+quad*4+r -> one b64 per kc
#pragma unroll
    for (int kc = 0; kc < 4; ++kc) {
      bf16x4 p4;
#pragma unroll
      for (int r = 0; r < 4; ++r) p4[r] = f2bf(s[kc * 4 + r]);
      *(bf16x4*)&Ps[wave][l16][kc * 16 + quad * 4] = p4;
    }

    // rescale O (alpha lives at query=l16; O rows are query=quad*4+r)
    float ar[4];
#pragma unroll
    for (int r = 0; r < 4; ++r) ar[r] = __shfl(alpha, quad * 4 + r);
#pragma unroll
    for (int dt = 0; dt < 4; ++dt)
#pragma unroll
      for (int r = 0; r < 4; ++r) o[dt][r] *= ar[r];

    asm volatile("s_waitcnt lgkmcnt(0)" ::: "memory");  // Ps RAW (wave-private)

    // ---- O += P V : A = Ps[l16][key], B = Vt[d][key] row-reads ----
#pragma unroll
    for (int kc2 = 0; kc2 < 2; ++kc2) {
      bf16x8 pa = *(const bf16x8*)&Ps[wave][l16][kc2 * 32 + quad * 8];
#pragma unroll
      for (int dt = 0; dt < 4; ++dt) {
        bf16x8 vb = *(const bf16x8*)&Vt[dt * 16 + l16][kc2 * 32 + quad * 8];
        o[dt] = __builtin_amdgcn_mfma_f32_16x16x32_bf16(pa, vb, o[dt], 0, 0, 0);
      }
    }
  }

  // epilogue: rows = query quad*4+r, cols = d = dt*16+l16
  float lr[4];
#pragma unroll
  for (int r = 0; r < 4; ++r) lr[r] = __shfl(l, quad * 4 + r);
#pragma unroll
  for (int dt = 0; dt < 4; ++dt)
#pragma unroll
    for (int r = 0; r < 4; ++r) {
      const size_t row = rowbase + q0 + quad * 4 + r;
      Out[row * D_ + h * DK_ + dt * 16 + l16] = f2bf(o[dt][r] / lr[r]);
    }
}

extern "C" void kernel_launch(void* const* d_in, const int* in_sizes, int n_in,
                              void* d_out, int out_size, void* d_ws, size_t ws_size,
                              hipStream_t stream) {
  (void)in_sizes; (void)n_in; (void)out_size; (void)ws_size;
  const float* x     = (const float*)d_in[0];
  const float* w_qkv = (const float*)d_in[1];
  const float* b_qkv = (const float*)d_in[2];
  const float* w_out = (const float*)d_in[3];
  const float* b_out = (const float*)d_in[4];
  float* out = (float*)d_out;

  const size_t NT = (size_t)B_ * L_;          // 4096 rows
  __bf16* qkv    = (__bf16*)d_ws;             // [4096,3072]
  __bf16* att    = qkv + NT * 3 * D_;         // [4096,1024]
  __bf16* xb     = att + NT * D_;             // [4096,1024]
  __bf16* wqkvT  = xb + NT * D_;              // [3072,1024]
  __bf16* woutT  = wqkvT + (size_t)3 * D_ * D_;  // [1024,1024]

  // conversions
  cvt_bf16<<<dim3((NT * D_) / 2048), dim3(256), 0, stream>>>(x, xb);
  transpose_cvt<<<dim3(3 * D_ / 32, D_ / 32), dim3(256), 0, stream>>>(w_qkv, wqkvT, D_, 3 * D_);
  transpose_cvt<<<dim3(D_ / 32, D_ / 32), dim3(256), 0, stream>>>(w_out, woutT, D_, D_);

  // QKV projection
  gemm_bt<__bf16><<<dim3(3 * D_ / 128, NT / 128), dim3(256), 0, stream>>>(
      xb, wqkvT, b_qkv, qkv, (int)NT, 3 * D_, D_);
  // attention
  attn<<<dim3(L_ / 32, H_, B_), dim3(128), 0, stream>>>(qkv, att);
  // output projection
  gemm_bt<float><<<dim3(D_ / 128, NT / 128), dim3(256), 0, stream>>>(
      att, woutT, b_out, out, (int)NT, D_, D_);
}